// Round 12
// baseline (394.769 us; speedup 1.0000x reference)
//
#include <hip/hip_runtime.h>

using bf16x8 = __attribute__((ext_vector_type(8))) __bf16;
using f32x4  = __attribute__((ext_vector_type(4))) float;

#define AS1 __attribute__((address_space(1)))
#define AS3 __attribute__((address_space(3)))

__device__ __forceinline__ unsigned short f2bf(float f) {
    unsigned int x = __float_as_uint(f);
    x += 0x7fffu + ((x >> 16) & 1u);   // RNE
    return (unsigned short)(x >> 16);
}

// bijective XCD-aware block remap (m204)
__device__ __forceinline__ int xcd_remap(int orig, int nwg) {
    int q = nwg >> 3, r = nwg & 7;
    int xcd = orig & 7, lin = orig >> 3;
    return (xcd < r ? xcd * (q + 1) : r * (q + 1) + (xcd - r) * q) + lin;
}

// ---- fused prep: Wqkv^T (1728) | Wproj^T (576) | x cvt (2048) | zero qn2/kn2 (24) ----
__global__ __launch_bounds__(256)
void prep_kernel(const float* __restrict__ x, ushort4* __restrict__ xbf,
                 const float* __restrict__ Wqkv, unsigned short* __restrict__ wqkvt,
                 const float* __restrict__ Wproj, unsigned short* __restrict__ wprojt,
                 float4* __restrict__ zbase) {
    __shared__ float tile[32][33];
    int bid = blockIdx.x, tid = threadIdx.x;
    if (bid < 2304) {
        const float* W; unsigned short* Wt; int K = 768, N; int bx, by;
        if (bid < 1728) { W = Wqkv; Wt = wqkvt; N = 2304; bx = bid % 72; by = bid / 72; }
        else            { int t = bid - 1728; W = Wproj; Wt = wprojt; N = 768; bx = t % 24; by = t / 24; }
        int n0 = bx << 5, k0 = by << 5;
        int tx = tid & 31, ty = tid >> 5;      // 32 x 8
#pragma unroll
        for (int i = 0; i < 32; i += 8)
            tile[ty + i][tx] = W[(size_t)(k0 + ty + i) * N + (n0 + tx)];
        __syncthreads();
#pragma unroll
        for (int i = 0; i < 32; i += 8)
            Wt[(size_t)(n0 + ty + i) * K + (k0 + tx)] = f2bf(tile[tx][ty + i]);
    } else if (bid < 4352) {
        int vb = bid - 2304;
        const float4* in = (const float4*)x;
        int n4 = 38535168 / 4;
        int stride = 2048 * 256;
        for (int i = vb * 256 + tid; i < n4; i += stride) {
            float4 v = in[i];
            ushort4 o;
            o.x = f2bf(v.x); o.y = f2bf(v.y); o.z = f2bf(v.z); o.w = f2bf(v.w);
            xbf[i] = o;
        }
    } else {
        // zero qn2+kn2: 6144 float4s over 24 blocks, one iter each
        int i = (bid - 4352) * 256 + tid;
        float4 zz4 = {0.f, 0.f, 0.f, 0.f};
        if (i < 6144) zbase[i] = zz4;
    }
}

// ================ proven m97-structure GEMM + XCD remap + NT C-store ================
__device__ __forceinline__ void stage_tile_128x64(const unsigned short* g, int ldK,
                                                  unsigned short* lds, int tid) {
#pragma unroll
    for (int r = 0; r < 4; ++r) {
        int i = (r << 8) + tid;              // 0..1023 : 16B chunks
        int row = i >> 3;
        int colb = (i & 7) << 4;
        int srcb = row * (ldK << 1) + (colb ^ ((row & 7) << 4));
        __builtin_amdgcn_global_load_lds(
            (AS1 unsigned int*)(unsigned long long)((const char*)g + srcb),
            (AS3 unsigned int*)((char*)lds + (i << 4)),
            16, 0, 0);
    }
}

__device__ __forceinline__ bf16x8 lds_read_swz(const unsigned short* base, int row, int kbyte) {
    int off = (row << 7) + (kbyte ^ ((row & 7) << 4));
    return *(const bf16x8*)((const char*)base + off);
}

__global__ __launch_bounds__(256, 4)
void gemm_bt_kernel(const unsigned short* __restrict__ A, const unsigned short* __restrict__ Bt,
                    unsigned short* __restrict__ obf, int M, int N, int K, int ntx) {
    __shared__ unsigned short As[128 * 64];
    __shared__ unsigned short Bs[128 * 64];
    int tid = threadIdx.x;
    int lane = tid & 63, w = tid >> 6;
    int wm = w >> 1, wn = w & 1;
    int wg = xcd_remap(blockIdx.x, gridDim.x);
    int bx = wg % ntx, by = wg / ntx;
    int m0 = by << 7, n0 = bx << 7;
    const unsigned short* Ag = A + (size_t)m0 * K;
    const unsigned short* Bg = Bt + (size_t)n0 * K;

    f32x4 zz = {0.f, 0.f, 0.f, 0.f};
    f32x4 acc[4][4];
#pragma unroll
    for (int a = 0; a < 4; ++a)
#pragma unroll
        for (int b = 0; b < 4; ++b) acc[a][b] = zz;

    for (int kb = 0; kb < K; kb += 64) {
        stage_tile_128x64(Ag + kb, K, As, tid);
        stage_tile_128x64(Bg + kb, K, Bs, tid);
        __syncthreads();
#pragma unroll
        for (int ks = 0; ks < 2; ++ks) {
            int kbyte = (ks << 6) + ((lane >> 4) << 4);
            bf16x8 af[4], bfr[4];
#pragma unroll
            for (int f = 0; f < 4; ++f)
                af[f] = lds_read_swz(As, (wm << 6) + (f << 4) + (lane & 15), kbyte);
#pragma unroll
            for (int f = 0; f < 4; ++f)
                bfr[f] = lds_read_swz(Bs, (wn << 6) + (f << 4) + (lane & 15), kbyte);
#pragma unroll
            for (int fm = 0; fm < 4; ++fm)
#pragma unroll
                for (int fn = 0; fn < 4; ++fn)
                    acc[fm][fn] = __builtin_amdgcn_mfma_f32_16x16x32_bf16(af[fm], bfr[fn], acc[fm][fn], 0, 0, 0);
        }
        __syncthreads();
    }

    int rbase = m0 + (wm << 6) + ((lane >> 4) << 2);
    int cbase = n0 + (wn << 6) + (lane & 15);
#pragma unroll
    for (int fm = 0; fm < 4; ++fm)
#pragma unroll
        for (int j = 0; j < 4; ++j) {
            size_t ro = (size_t)(rbase + (fm << 4) + j) * N;
#pragma unroll
            for (int fn = 0; fn < 4; ++fn)
                __builtin_nontemporal_store(f2bf(acc[fm][fn][j]), &obf[ro + cbase + (fn << 4)]);
        }
}

// ================ fused V@M projection GEMM: out[b] = qkvV_b[3136,768] @ MT_b^T + bias ==========
__global__ __launch_bounds__(256, 2)
void gemm_v_proj_kernel(const unsigned short* __restrict__ qkv, const unsigned short* __restrict__ MT,
                        float* __restrict__ out, const float* __restrict__ bias) {
    __shared__ unsigned short As[128 * 64];
    __shared__ unsigned short Bs[128 * 64];
    int tid = threadIdx.x;
    int lane = tid & 63, w = tid >> 6;
    int wm = w >> 1, wn = w & 1;
    int wg = xcd_remap(blockIdx.x, gridDim.x);   // nwg = 16*25*6 = 2400
    int bx = wg % 6;
    int t2 = wg / 6;
    int mt = t2 % 25, b = t2 / 25;
    int m0 = mt << 7, n0 = bx << 7;
    const unsigned short* Ab = qkv + (size_t)b * 3136 * 2304 + 1536;   // V block (ushort units)
    const unsigned short* Bg = MT + (size_t)b * 589824 + (size_t)n0 * 768;

    f32x4 zz = {0.f, 0.f, 0.f, 0.f};
    f32x4 acc[4][4];
#pragma unroll
    for (int a = 0; a < 4; ++a)
#pragma unroll
        for (int c = 0; c < 4; ++c) acc[a][c] = zz;

    for (int kb = 0; kb < 768; kb += 64) {
#pragma unroll
        for (int r = 0; r < 4; ++r) {
            int i = (r << 8) + tid;
            int row = i >> 3, slot = i & 7;
            int rg = m0 + row; if (rg > 3135) rg = 3135;
            const char* src = (const char*)(Ab + (size_t)rg * 2304 + kb) + ((slot ^ (row & 7)) << 4);
            __builtin_amdgcn_global_load_lds(
                (AS1 unsigned int*)(unsigned long long)src,
                (AS3 unsigned int*)((char*)As + (i << 4)), 16, 0, 0);
        }
        stage_tile_128x64(Bg + kb, 768, Bs, tid);
        __syncthreads();
#pragma unroll
        for (int ks = 0; ks < 2; ++ks) {
            int kbyte = (ks << 6) + ((lane >> 4) << 4);
            bf16x8 af[4], bfr[4];
#pragma unroll
            for (int f = 0; f < 4; ++f)
                af[f] = lds_read_swz(As, (wm << 6) + (f << 4) + (lane & 15), kbyte);
#pragma unroll
            for (int f = 0; f < 4; ++f)
                bfr[f] = lds_read_swz(Bs, (wn << 6) + (f << 4) + (lane & 15), kbyte);
#pragma unroll
            for (int fm = 0; fm < 4; ++fm)
#pragma unroll
                for (int fn = 0; fn < 4; ++fn)
                    acc[fm][fn] = __builtin_amdgcn_mfma_f32_16x16x32_bf16(af[fm], bfr[fn], acc[fm][fn], 0, 0, 0);
        }
        __syncthreads();
    }

    int rloc = m0 + (wm << 6) + ((lane >> 4) << 2);
    int cbase = n0 + (wn << 6) + (lane & 15);
    float bv[4];
#pragma unroll
    for (int fn = 0; fn < 4; ++fn) bv[fn] = bias[cbase + (fn << 4)];
#pragma unroll
    for (int fm = 0; fm < 4; ++fm)
#pragma unroll
        for (int j = 0; j < 4; ++j) {
            int rr = rloc + (fm << 4) + j;
            if (rr < 3136) {
                size_t ro = ((size_t)b * 3136 + rr) * 768;
#pragma unroll
                for (int fn = 0; fn < 4; ++fn)
                    __builtin_nontemporal_store(acc[fm][fn][j] + bv[fn], &out[ro + cbase + (fn << 4)]);
            }
        }
}

// ---------------- covariance via MFMA: partial S to Sp[chunk][bh][9216], no atomics ----------------
__global__ __launch_bounds__(256)
void cov_mfma_kernel(const unsigned short* __restrict__ qkv, float* __restrict__ Sp,
                     float* __restrict__ qn2, float* __restrict__ kn2) {
    __shared__ unsigned short Kl[96 * 40];   // [channel][token], stride 40 ushorts (80B)
    __shared__ unsigned short Ql[96 * 40];
    int bh = blockIdx.x;
    int b = bh >> 3, h = bh & 7;
    int tok0 = blockIdx.y * 448;
    int tid = threadIdx.x;
    int lane = tid & 63, w = tid >> 6;
    int wr = w & 1, wc = w >> 1;
    int rot = tid & 7;

    f32x4 zz = {0.f, 0.f, 0.f, 0.f};
    f32x4 acc[3][3];
#pragma unroll
    for (int a = 0; a < 3; ++a)
#pragma unroll
        for (int c = 0; c < 3; ++c) acc[a][c] = zz;
    float qn = 0.f, kn = 0.f;

    const uint4* qg = (const uint4*)qkv;   // qkv row = 288 uint4

    for (int step = 0; step < 14; ++step) {
        int tokBase = b * 3136 + tok0 + (step << 5);
        __syncthreads();
#pragma unroll
        for (int r = 0; r < 3; ++r) {
            int idx = (r << 8) + tid;          // 0..767 ; 0..383 = Q, 384..767 = K
            int isK = idx >= 384;
            int j = isK ? idx - 384 : idx;
            int tok = j / 12, c = j % 12;
            uint4 u = qg[(size_t)(tokBase + tok) * 288 + h * 12 + (isK ? 96 : 0) + c];
            unsigned short* dst = isK ? Kl : Ql;
            const unsigned short* us = (const unsigned short*)&u;
#pragma unroll
            for (int i = 0; i < 8; ++i) {
                int e = (i + rot) & 7;
                dst[(c * 8 + e) * 40 + tok] = us[e];
            }
        }
        __syncthreads();
        if (tid < 96) {
#pragma unroll
            for (int t = 0; t < 4; ++t) {
                bf16x8 v = *(const bf16x8*)((const char*)Ql + tid * 80 + (t << 4));
#pragma unroll
                for (int i = 0; i < 8; ++i) { float f = (float)v[i]; qn = fmaf(f, f, qn); }
            }
        } else if (tid >= 128 && tid < 224) {
            int c = tid - 128;
#pragma unroll
            for (int t = 0; t < 4; ++t) {
                bf16x8 v = *(const bf16x8*)((const char*)Kl + c * 80 + (t << 4));
#pragma unroll
                for (int i = 0; i < 8; ++i) { float f = (float)v[i]; kn = fmaf(f, f, kn); }
            }
        }
        int kbyte = (lane >> 4) << 4;
        bf16x8 af[3], bfv[3];
#pragma unroll
        for (int f = 0; f < 3; ++f)
            af[f] = *(const bf16x8*)((const char*)Kl + (wr * 48 + f * 16 + (lane & 15)) * 80 + kbyte);
#pragma unroll
        for (int f = 0; f < 3; ++f)
            bfv[f] = *(const bf16x8*)((const char*)Ql + (wc * 48 + f * 16 + (lane & 15)) * 80 + kbyte);
#pragma unroll
        for (int fm = 0; fm < 3; ++fm)
#pragma unroll
            for (int fn = 0; fn < 3; ++fn)
                acc[fm][fn] = __builtin_amdgcn_mfma_f32_16x16x32_bf16(af[fm], bfv[fn], acc[fm][fn], 0, 0, 0);
    }

    // plain stores to this block's private partial
    float* Sb = Sp + ((size_t)blockIdx.y * 128 + bh) * 9216;
    int rloc = wr * 48 + ((lane >> 4) << 2);
    int cloc = wc * 48 + (lane & 15);
#pragma unroll
    for (int fm = 0; fm < 3; ++fm)
#pragma unroll
        for (int fn = 0; fn < 3; ++fn)
#pragma unroll
            for (int j = 0; j < 4; ++j)
                Sb[(rloc + fm * 16 + j) * 96 + cloc + fn * 16] = acc[fm][fn][j];
    if (tid < 96) atomicAdd(&qn2[bh * 96 + tid], qn);
    if (tid >= 128 && tid < 224) atomicAdd(&kn2[bh * 96 + tid - 128], kn);
}

// ---------------- softmax (reduces 7 partials) -> attnT[e][c] (transposed, bf16) ----------------
__global__ __launch_bounds__(128)
void softmax_kernel(const float* __restrict__ Sp, const float* __restrict__ qn2,
                    const float* __restrict__ kn2, const float* __restrict__ temp,
                    unsigned short* __restrict__ attnT) {
    int bh = blockIdx.x, h = bh & 7;
    __shared__ float Sl[96 * 97];
    __shared__ float qinv[96];
    int tid = threadIdx.x;
    for (int i = tid; i < 9216; i += 128) {
        float s = 0.f;
#pragma unroll
        for (int ch = 0; ch < 7; ++ch)
            s += Sp[((size_t)ch * 128 + bh) * 9216 + i];
        Sl[(i / 96) * 97 + (i % 96)] = s;
    }
    if (tid < 96) qinv[tid] = 1.f / fmaxf(sqrtf(qn2[bh * 96 + tid]), 1e-12f);
    __syncthreads();
    if (tid < 96) {
        int c = tid;
        float scale = (1.f / fmaxf(sqrtf(kn2[bh * 96 + c]), 1e-12f)) * temp[h];
        float* row = &Sl[c * 97];
        float mx = -3.4e38f;
        for (int e = 0; e < 96; ++e) {
            float v = row[e] * scale * qinv[e];
            row[e] = v;
            mx = fmaxf(mx, v);
        }
        float s = 0.f;
        for (int e = 0; e < 96; ++e) {
            float p = __expf(row[e] - mx);
            row[e] = p;
            s += p;
        }
        float inv = 1.f / s;
        unsigned short* ab = attnT + (size_t)bh * 9216;
        for (int e = 0; e < 96; ++e) ab[e * 96 + c] = f2bf(row[e] * inv);
    }
}

// ---------------- M precompute: MT[b][o][h*96+e] = sum_c attnT[bh][e][c] * wprojt[o][h*96+c] ----
__global__ __launch_bounds__(256)
void attn_M_kernel(const unsigned short* __restrict__ attnT, const unsigned short* __restrict__ wprojt,
                   unsigned short* __restrict__ MT) {
    int bh = blockIdx.x >> 2, oc = blockIdx.x & 3;
    int b = bh >> 3, h = bh & 7;
    int tid = threadIdx.x, lane = tid & 63, w = tid >> 6;
    int o0 = oc * 192 + w * 48;
    const unsigned short* At = attnT + (size_t)bh * 9216;

    f32x4 zz = {0.f, 0.f, 0.f, 0.f};
    f32x4 acc[6][3];
#pragma unroll
    for (int f = 0; f < 6; ++f)
#pragma unroll
        for (int g = 0; g < 3; ++g) acc[f][g] = zz;

#pragma unroll
    for (int ks = 0; ks < 3; ++ks) {
        int koff = ks * 32 + ((lane >> 4) << 3);
        bf16x8 a[6], bb[3];
#pragma unroll
        for (int f = 0; f < 6; ++f)
            a[f] = *(const bf16x8*)(At + (size_t)(f * 16 + (lane & 15)) * 96 + koff);
#pragma unroll
        for (int g = 0; g < 3; ++g)
            bb[g] = *(const bf16x8*)(wprojt + (size_t)(o0 + g * 16 + (lane & 15)) * 768 + h * 96 + koff);
#pragma unroll
        for (int f = 0; f < 6; ++f)
#pragma unroll
            for (int g = 0; g < 3; ++g)
                acc[f][g] = __builtin_amdgcn_mfma_f32_16x16x32_bf16(a[f], bb[g], acc[f][g], 0, 0, 0);
    }

#pragma unroll
    for (int f = 0; f < 6; ++f)
#pragma unroll
        for (int g = 0; g < 3; ++g) {
            int e = f * 16 + ((lane >> 4) << 2);
            int o = o0 + g * 16 + (lane & 15);
            ushort4 pk;
            pk.x = f2bf(acc[f][g][0]); pk.y = f2bf(acc[f][g][1]);
            pk.z = f2bf(acc[f][g][2]); pk.w = f2bf(acc[f][g][3]);
            *(ushort4*)&MT[((size_t)b * 768 + o) * 768 + h * 96 + e] = pk;
        }
}

// ---------------- launch ----------------
extern "C" void kernel_launch(void* const* d_in, const int* in_sizes, int n_in,
                              void* d_out, int out_size, void* d_ws, size_t ws_size,
                              hipStream_t stream) {
    const float* x     = (const float*)d_in[0];
    const float* Wqkv  = (const float*)d_in[1];
    const float* temp  = (const float*)d_in[2];
    const float* Wproj = (const float*)d_in[3];
    const float* bproj = (const float*)d_in[4];
    float* out = (float*)d_out;
    char* ws = (char*)d_ws;

    unsigned short* xbf    = (unsigned short*)(ws);                 //  77,070,336
    unsigned short* qkvbf  = (unsigned short*)(ws + 77070336);      // 231,211,008
    unsigned short* wqkvt  = (unsigned short*)(ws + 308281344);     //   3,538,944
    unsigned short* wprojt = (unsigned short*)(ws + 311820288);     //   1,179,648
    float*          qn2    = (float*)        (ws + 317718528);      //      49,152
    float*          kn2    = (float*)        (ws + 317767680);      //      49,152
    unsigned short* attnT  = (unsigned short*)(ws + 317816832);     //   2,359,296
    // dead-xbf region reuse (xbf dead after GEMM1):
    unsigned short* MT     = xbf;                                   //  18,874,368
    float*          Sp     = (float*)(ws + 20971520);               //  33,030,144 (in xbf region)

    // fused prep: Wqkv^T | Wproj^T | x cvt | zero qn2/kn2
    prep_kernel<<<4376, 256, 0, stream>>>(x, (ushort4*)xbf, Wqkv, wqkvt, Wproj, wprojt,
                                          (float4*)qn2);

    // qkv = x @ Wqkv  [50176 x 2304]: 392x18 tiles of 128^2, XCD-remapped 1D grid
    gemm_bt_kernel<<<392 * 18, 256, 0, stream>>>(xbf, wqkvt, qkvbf, 50176, 2304, 768, 18);
    // Sp[chunk][bh] = partial K^T Q, + channel norms
    cov_mfma_kernel<<<dim3(128, 7), 256, 0, stream>>>(qkvbf, Sp, qn2, kn2);
    // attnT = softmax(sum_ch Sp / (|k||q|) * temp)^T
    softmax_kernel<<<128, 128, 0, stream>>>(Sp, qn2, kn2, temp, attnT);
    // MT[b][o][he] = sum_c attn * Wproj
    attn_M_kernel<<<512, 256, 0, stream>>>(attnT, wprojt, MT);
    // out[b] = qkvV_b @ MT_b^T + bias
    gemm_v_proj_kernel<<<2400, 256, 0, stream>>>(qkvbf, MT, out, bproj);
}

// Round 13
// 382.286 us; speedup vs baseline: 1.0327x; 1.0327x over previous
//
#include <hip/hip_runtime.h>

using bf16x8 = __attribute__((ext_vector_type(8))) __bf16;
using f32x4  = __attribute__((ext_vector_type(4))) float;

#define AS1 __attribute__((address_space(1)))
#define AS3 __attribute__((address_space(3)))

__device__ __forceinline__ unsigned short f2bf(float f) {
    unsigned int x = __float_as_uint(f);
    x += 0x7fffu + ((x >> 16) & 1u);   // RNE
    return (unsigned short)(x >> 16);
}

// bijective XCD-aware block remap (m204)
__device__ __forceinline__ int xcd_remap(int orig, int nwg) {
    int q = nwg >> 3, r = nwg & 7;
    int xcd = orig & 7, lin = orig >> 3;
    return (xcd < r ? xcd * (q + 1) : r * (q + 1) + (xcd - r) * q) + lin;
}

// ---- fused prep: Wqkv^T (1728) | Wproj^T (576) | x cvt (2048) | zero S/qn2/kn2 (294) ----
__global__ __launch_bounds__(256)
void prep_kernel(const float* __restrict__ x, ushort4* __restrict__ xbf,
                 const float* __restrict__ Wqkv, unsigned short* __restrict__ wqkvt,
                 const float* __restrict__ Wproj, unsigned short* __restrict__ wprojt,
                 float4* __restrict__ zbase) {
    __shared__ float tile[32][33];
    int bid = blockIdx.x, tid = threadIdx.x;
    if (bid < 2304) {
        const float* W; unsigned short* Wt; int K = 768, N; int bx, by;
        if (bid < 1728) { W = Wqkv; Wt = wqkvt; N = 2304; bx = bid % 72; by = bid / 72; }
        else            { int t = bid - 1728; W = Wproj; Wt = wprojt; N = 768; bx = t % 24; by = t / 24; }
        int n0 = bx << 5, k0 = by << 5;
        int tx = tid & 31, ty = tid >> 5;      // 32 x 8
#pragma unroll
        for (int i = 0; i < 32; i += 8)
            tile[ty + i][tx] = W[(size_t)(k0 + ty + i) * N + (n0 + tx)];
        __syncthreads();
#pragma unroll
        for (int i = 0; i < 32; i += 8)
            Wt[(size_t)(n0 + ty + i) * K + (k0 + tx)] = f2bf(tile[tx][ty + i]);
    } else if (bid < 4352) {
        int vb = bid - 2304;
        const float4* in = (const float4*)x;
        int n4 = 38535168 / 4;
        int stride = 2048 * 256;
        for (int i = vb * 256 + tid; i < n4; i += stride) {
            float4 v = in[i];
            ushort4 o;
            o.x = f2bf(v.x); o.y = f2bf(v.y); o.z = f2bf(v.z); o.w = f2bf(v.w);
            xbf[i] = o;
        }
    } else {
        // zero Sbuf+qn2+kn2: 301056 float4s over 294 blocks
        int z = bid - 4352;
        float4 zz4 = {0.f, 0.f, 0.f, 0.f};
        for (int i = z * 256 + tid; i < 301056; i += 294 * 256) zbase[i] = zz4;
    }
}

// ================ proven m97-structure GEMM + XCD remap + NT C-store ================
__device__ __forceinline__ void stage_tile_128x64(const unsigned short* g, int ldK,
                                                  unsigned short* lds, int tid) {
#pragma unroll
    for (int r = 0; r < 4; ++r) {
        int i = (r << 8) + tid;              // 0..1023 : 16B chunks
        int row = i >> 3;
        int colb = (i & 7) << 4;
        int srcb = row * (ldK << 1) + (colb ^ ((row & 7) << 4));
        __builtin_amdgcn_global_load_lds(
            (AS1 unsigned int*)(unsigned long long)((const char*)g + srcb),
            (AS3 unsigned int*)((char*)lds + (i << 4)),
            16, 0, 0);
    }
}

__device__ __forceinline__ bf16x8 lds_read_swz(const unsigned short* base, int row, int kbyte) {
    int off = (row << 7) + (kbyte ^ ((row & 7) << 4));
    return *(const bf16x8*)((const char*)base + off);
}

__global__ __launch_bounds__(256, 2)
void gemm_bt_kernel(const unsigned short* __restrict__ A, const unsigned short* __restrict__ Bt,
                    unsigned short* __restrict__ obf, int M, int N, int K, int ntx) {
    __shared__ unsigned short As[128 * 64];
    __shared__ unsigned short Bs[128 * 64];
    int tid = threadIdx.x;
    int lane = tid & 63, w = tid >> 6;
    int wm = w >> 1, wn = w & 1;
    int wg = xcd_remap(blockIdx.x, gridDim.x);
    int bx = wg % ntx, by = wg / ntx;
    int m0 = by << 7, n0 = bx << 7;
    const unsigned short* Ag = A + (size_t)m0 * K;
    const unsigned short* Bg = Bt + (size_t)n0 * K;

    f32x4 zz = {0.f, 0.f, 0.f, 0.f};
    f32x4 acc[4][4];
#pragma unroll
    for (int a = 0; a < 4; ++a)
#pragma unroll
        for (int b = 0; b < 4; ++b) acc[a][b] = zz;

    for (int kb = 0; kb < K; kb += 64) {
        stage_tile_128x64(Ag + kb, K, As, tid);
        stage_tile_128x64(Bg + kb, K, Bs, tid);
        __syncthreads();
#pragma unroll
        for (int ks = 0; ks < 2; ++ks) {
            int kbyte = (ks << 6) + ((lane >> 4) << 4);
            bf16x8 af[4], bfr[4];
#pragma unroll
            for (int f = 0; f < 4; ++f)
                af[f] = lds_read_swz(As, (wm << 6) + (f << 4) + (lane & 15), kbyte);
#pragma unroll
            for (int f = 0; f < 4; ++f)
                bfr[f] = lds_read_swz(Bs, (wn << 6) + (f << 4) + (lane & 15), kbyte);
#pragma unroll
            for (int fm = 0; fm < 4; ++fm)
#pragma unroll
                for (int fn = 0; fn < 4; ++fn)
                    acc[fm][fn] = __builtin_amdgcn_mfma_f32_16x16x32_bf16(af[fm], bfr[fn], acc[fm][fn], 0, 0, 0);
        }
        __syncthreads();
    }

    int rbase = m0 + (wm << 6) + ((lane >> 4) << 2);
    int cbase = n0 + (wn << 6) + (lane & 15);
#pragma unroll
    for (int fm = 0; fm < 4; ++fm)
#pragma unroll
        for (int j = 0; j < 4; ++j) {
            size_t ro = (size_t)(rbase + (fm << 4) + j) * N;
#pragma unroll
            for (int fn = 0; fn < 4; ++fn)
                __builtin_nontemporal_store(f2bf(acc[fm][fn][j]), &obf[ro + cbase + (fn << 4)]);
        }
}

// ================ fused V@M projection GEMM: out[b] = qkvV_b[3136,768] @ MT_b^T + bias ==========
__global__ __launch_bounds__(256, 2)
void gemm_v_proj_kernel(const unsigned short* __restrict__ qkv, const unsigned short* __restrict__ MT,
                        float* __restrict__ out, const float* __restrict__ bias) {
    __shared__ unsigned short As[128 * 64];
    __shared__ unsigned short Bs[128 * 64];
    int tid = threadIdx.x;
    int lane = tid & 63, w = tid >> 6;
    int wm = w >> 1, wn = w & 1;
    int wg = xcd_remap(blockIdx.x, gridDim.x);   // nwg = 16*25*6 = 2400
    int bx = wg % 6;
    int t2 = wg / 6;
    int mt = t2 % 25, b = t2 / 25;
    int m0 = mt << 7, n0 = bx << 7;
    const unsigned short* Ab = qkv + (size_t)b * 3136 * 2304 + 1536;   // V block (ushort units)
    const unsigned short* Bg = MT + (size_t)b * 589824 + (size_t)n0 * 768;

    f32x4 zz = {0.f, 0.f, 0.f, 0.f};
    f32x4 acc[4][4];
#pragma unroll
    for (int a = 0; a < 4; ++a)
#pragma unroll
        for (int c = 0; c < 4; ++c) acc[a][c] = zz;

    for (int kb = 0; kb < 768; kb += 64) {
#pragma unroll
        for (int r = 0; r < 4; ++r) {
            int i = (r << 8) + tid;
            int row = i >> 3, slot = i & 7;
            int rg = m0 + row; if (rg > 3135) rg = 3135;
            const char* src = (const char*)(Ab + (size_t)rg * 2304 + kb) + ((slot ^ (row & 7)) << 4);
            __builtin_amdgcn_global_load_lds(
                (AS1 unsigned int*)(unsigned long long)src,
                (AS3 unsigned int*)((char*)As + (i << 4)), 16, 0, 0);
        }
        stage_tile_128x64(Bg + kb, 768, Bs, tid);
        __syncthreads();
#pragma unroll
        for (int ks = 0; ks < 2; ++ks) {
            int kbyte = (ks << 6) + ((lane >> 4) << 4);
            bf16x8 af[4], bfr[4];
#pragma unroll
            for (int f = 0; f < 4; ++f)
                af[f] = lds_read_swz(As, (wm << 6) + (f << 4) + (lane & 15), kbyte);
#pragma unroll
            for (int f = 0; f < 4; ++f)
                bfr[f] = lds_read_swz(Bs, (wn << 6) + (f << 4) + (lane & 15), kbyte);
#pragma unroll
            for (int fm = 0; fm < 4; ++fm)
#pragma unroll
                for (int fn = 0; fn < 4; ++fn)
                    acc[fm][fn] = __builtin_amdgcn_mfma_f32_16x16x32_bf16(af[fm], bfr[fn], acc[fm][fn], 0, 0, 0);
        }
        __syncthreads();
    }

    int rloc = m0 + (wm << 6) + ((lane >> 4) << 2);
    int cbase = n0 + (wn << 6) + (lane & 15);
    float bv[4];
#pragma unroll
    for (int fn = 0; fn < 4; ++fn) bv[fn] = bias[cbase + (fn << 4)];
#pragma unroll
    for (int fm = 0; fm < 4; ++fm)
#pragma unroll
        for (int j = 0; j < 4; ++j) {
            int rr = rloc + (fm << 4) + j;
            if (rr < 3136) {
                size_t ro = ((size_t)b * 3136 + rr) * 768;
#pragma unroll
                for (int fn = 0; fn < 4; ++fn)
                    out[ro + cbase + (fn << 4)] = acc[fm][fn][j] + bv[fn];
            }
        }
}

// ---------------- covariance via MFMA (R11-proven: LDS transpose, atomics) ----------------
__global__ __launch_bounds__(256)
void cov_mfma_kernel(const unsigned short* __restrict__ qkv, float* __restrict__ S,
                     float* __restrict__ qn2, float* __restrict__ kn2) {
    __shared__ unsigned short Kl[96 * 40];   // [channel][token], stride 40 ushorts (80B)
    __shared__ unsigned short Ql[96 * 40];
    int bh = blockIdx.x;
    int b = bh >> 3, h = bh & 7;
    int tok0 = blockIdx.y * 448;
    int tid = threadIdx.x;
    int lane = tid & 63, w = tid >> 6;
    int wr = w & 1, wc = w >> 1;
    int rot = tid & 7;

    f32x4 zz = {0.f, 0.f, 0.f, 0.f};
    f32x4 acc[3][3];
#pragma unroll
    for (int a = 0; a < 3; ++a)
#pragma unroll
        for (int c = 0; c < 3; ++c) acc[a][c] = zz;
    float qn = 0.f, kn = 0.f;

    const uint4* qg = (const uint4*)qkv;   // qkv row = 288 uint4

    for (int step = 0; step < 14; ++step) {
        int tokBase = b * 3136 + tok0 + (step << 5);
        __syncthreads();
#pragma unroll
        for (int r = 0; r < 3; ++r) {
            int idx = (r << 8) + tid;          // 0..767 ; 0..383 = Q, 384..767 = K
            int isK = idx >= 384;
            int j = isK ? idx - 384 : idx;
            int tok = j / 12, c = j % 12;
            uint4 u = qg[(size_t)(tokBase + tok) * 288 + h * 12 + (isK ? 96 : 0) + c];
            unsigned short* dst = isK ? Kl : Ql;
            const unsigned short* us = (const unsigned short*)&u;
#pragma unroll
            for (int i = 0; i < 8; ++i) {
                int e = (i + rot) & 7;
                dst[(c * 8 + e) * 40 + tok] = us[e];
            }
        }
        __syncthreads();
        if (tid < 96) {
#pragma unroll
            for (int t = 0; t < 4; ++t) {
                bf16x8 v = *(const bf16x8*)((const char*)Ql + tid * 80 + (t << 4));
#pragma unroll
                for (int i = 0; i < 8; ++i) { float f = (float)v[i]; qn = fmaf(f, f, qn); }
            }
        } else if (tid >= 128 && tid < 224) {
            int c = tid - 128;
#pragma unroll
            for (int t = 0; t < 4; ++t) {
                bf16x8 v = *(const bf16x8*)((const char*)Kl + c * 80 + (t << 4));
#pragma unroll
                for (int i = 0; i < 8; ++i) { float f = (float)v[i]; kn = fmaf(f, f, kn); }
            }
        }
        int kbyte = (lane >> 4) << 4;
        bf16x8 af[3], bfv[3];
#pragma unroll
        for (int f = 0; f < 3; ++f)
            af[f] = *(const bf16x8*)((const char*)Kl + (wr * 48 + f * 16 + (lane & 15)) * 80 + kbyte);
#pragma unroll
        for (int f = 0; f < 3; ++f)
            bfv[f] = *(const bf16x8*)((const char*)Ql + (wc * 48 + f * 16 + (lane & 15)) * 80 + kbyte);
#pragma unroll
        for (int fm = 0; fm < 3; ++fm)
#pragma unroll
            for (int fn = 0; fn < 3; ++fn)
                acc[fm][fn] = __builtin_amdgcn_mfma_f32_16x16x32_bf16(af[fm], bfv[fn], acc[fm][fn], 0, 0, 0);
    }

    float* Sb = S + (size_t)bh * 9216;
    int rloc = wr * 48 + ((lane >> 4) << 2);
    int cloc = wc * 48 + (lane & 15);
#pragma unroll
    for (int fm = 0; fm < 3; ++fm)
#pragma unroll
        for (int fn = 0; fn < 3; ++fn)
#pragma unroll
            for (int j = 0; j < 4; ++j)
                atomicAdd(&Sb[(rloc + fm * 16 + j) * 96 + cloc + fn * 16], acc[fm][fn][j]);
    if (tid < 96) atomicAdd(&qn2[bh * 96 + tid], qn);
    if (tid >= 128 && tid < 224) atomicAdd(&kn2[bh * 96 + tid - 128], kn);
}

// ------- merged softmax + M precompute, 512 blocks (4 per bh, redundant softmax) -------
// block = (bh, oc): softmax(S[bh]) -> At (LDS), then MT o-chunk oc via MFMA.
__global__ __launch_bounds__(256)
void softmax_M_kernel(const float* __restrict__ S, const float* __restrict__ qn2,
                      const float* __restrict__ kn2, const float* __restrict__ temp,
                      const unsigned short* __restrict__ wprojt, unsigned short* __restrict__ MT) {
    int bh = blockIdx.x >> 2, oc = blockIdx.x & 3;
    int h = bh & 7, b = bh >> 3;
    __shared__ float Sl[96 * 97];
    __shared__ float qinv[96];
    __shared__ unsigned short At[96 * 96];   // attnT[e][c] bf16
    int tid = threadIdx.x, lane = tid & 63, w = tid >> 6;
    int l15 = lane & 15;
    const float* Sg = S + (size_t)bh * 9216;
    for (int i = tid; i < 9216; i += 256) Sl[(i / 96) * 97 + (i % 96)] = Sg[i];
    if (tid < 96) qinv[tid] = 1.f / fmaxf(sqrtf(qn2[bh * 96 + tid]), 1e-12f);
    __syncthreads();
    if (tid < 96) {
        int c = tid;
        float scale = (1.f / fmaxf(sqrtf(kn2[bh * 96 + c]), 1e-12f)) * temp[h];
        float* row = &Sl[c * 97];
        float mx = -3.4e38f;
        for (int e = 0; e < 96; ++e) {
            float v = row[e] * scale * qinv[e];
            row[e] = v;
            mx = fmaxf(mx, v);
        }
        float s = 0.f;
        for (int e = 0; e < 96; ++e) {
            float p = __expf(row[e] - mx);
            row[e] = p;
            s += p;
        }
        float inv = 1.f / s;
        for (int e = 0; e < 96; ++e) At[e * 96 + c] = f2bf(row[e] * inv);
    }
    __syncthreads();

    // this block's o-chunk: o0 = oc*192 + w*48
    int o0 = oc * 192 + w * 48;
    f32x4 zz = {0.f, 0.f, 0.f, 0.f};
    f32x4 acc[6][3];
#pragma unroll
    for (int f = 0; f < 6; ++f)
#pragma unroll
        for (int g = 0; g < 3; ++g) acc[f][g] = zz;
#pragma unroll
    for (int ks = 0; ks < 3; ++ks) {
        int koff = ks * 32 + ((lane >> 4) << 3);
        bf16x8 a[6], bb[3];
#pragma unroll
        for (int f = 0; f < 6; ++f)
            a[f] = *(const bf16x8*)(At + (f * 16 + l15) * 96 + koff);
#pragma unroll
        for (int g = 0; g < 3; ++g)
            bb[g] = *(const bf16x8*)(wprojt + (size_t)(o0 + g * 16 + l15) * 768 + h * 96 + koff);
#pragma unroll
        for (int f = 0; f < 6; ++f)
#pragma unroll
            for (int g = 0; g < 3; ++g)
                acc[f][g] = __builtin_amdgcn_mfma_f32_16x16x32_bf16(a[f], bb[g], acc[f][g], 0, 0, 0);
    }
#pragma unroll
    for (int f = 0; f < 6; ++f)
#pragma unroll
        for (int g = 0; g < 3; ++g) {
            int e = f * 16 + ((lane >> 4) << 2);
            int o = o0 + g * 16 + l15;
            ushort4 pk;
            pk.x = f2bf(acc[f][g][0]); pk.y = f2bf(acc[f][g][1]);
            pk.z = f2bf(acc[f][g][2]); pk.w = f2bf(acc[f][g][3]);
            *(ushort4*)&MT[((size_t)b * 768 + o) * 768 + h * 96 + e] = pk;
        }
}

// ---------------- launch ----------------
extern "C" void kernel_launch(void* const* d_in, const int* in_sizes, int n_in,
                              void* d_out, int out_size, void* d_ws, size_t ws_size,
                              hipStream_t stream) {
    const float* x     = (const float*)d_in[0];
    const float* Wqkv  = (const float*)d_in[1];
    const float* temp  = (const float*)d_in[2];
    const float* Wproj = (const float*)d_in[3];
    const float* bproj = (const float*)d_in[4];
    float* out = (float*)d_out;
    char* ws = (char*)d_ws;

    unsigned short* xbf    = (unsigned short*)(ws);                 //  77,070,336
    unsigned short* qkvbf  = (unsigned short*)(ws + 77070336);      // 231,211,008
    unsigned short* wqkvt  = (unsigned short*)(ws + 308281344);     //   3,538,944
    unsigned short* wprojt = (unsigned short*)(ws + 311820288);     //   1,179,648
    float*          Sbuf   = (float*)        (ws + 312999936);      //   4,718,592
    float*          qn2    = (float*)        (ws + 317718528);      //      49,152
    float*          kn2    = (float*)        (ws + 317767680);      //      49,152
    unsigned short* MT     = xbf;  // alias: x_bf16 dead after GEMM1

    // fused prep: Wqkv^T | Wproj^T | x cvt | zero Sbuf/qn2/kn2
    prep_kernel<<<4646, 256, 0, stream>>>(x, (ushort4*)xbf, Wqkv, wqkvt, Wproj, wprojt,
                                          (float4*)Sbuf);

    // qkv = x @ Wqkv  [50176 x 2304]: 392x18 tiles of 128^2, XCD-remapped 1D grid
    gemm_bt_kernel<<<392 * 18, 256, 0, stream>>>(xbf, wqkvt, qkvbf, 50176, 2304, 768, 18);
    // S = K^T Q (per bh), + channel norms
    cov_mfma_kernel<<<dim3(128, 7), 256, 0, stream>>>(qkvbf, Sbuf, qn2, kn2);
    // softmax + MT precompute (merged, 4 blocks/bh)
    softmax_M_kernel<<<512, 256, 0, stream>>>(Sbuf, qn2, kn2, temp, wprojt, MT);
    // out[b] = qkvV_b @ MT_b^T + bias
    gemm_v_proj_kernel<<<2400, 256, 0, stream>>>(qkvbf, MT, out, bproj);
}